// Round 1
// 216.568 us; speedup vs baseline: 1.3329x; 1.3329x over previous
//
#include <hip/hip_runtime.h>
#include <float.h>
#include <stdint.h>

// MimiEuclideanCodebook: argmin_k ||x_n - e_k||^2 then gather e_k.
// R9 = occupancy + LDS-linearization rewrite of mm_kernel:
//  - 512 threads (8 waves, 2/SIMD) instead of 256 (1/SIMD): latency hiding.
//  - A LDS layout as*4096 + row*32 + q*8: fragment reads are contiguous
//    1KB wave accesses -> zero bank conflicts, no padding (A = 128KB exact).
//  - B layout krow*32 + q*8, staged linearly (4 thr/row, 64B segments).
//  - Pass reorder: each staged eh chunk feeds BOTH xh*eh and xl*eh MFMAs
//    -> 16 stages per k-tile (was 24), 33% fewer barriers / B restages.
// Split-precision virtual K=768: xh*eh + xl*eh + xh*el. Top-2 carried in
// registers across k-tiles; exact-fp32 repair for rows with gap < DELTA.

#define EPSILON 1e-5f
#define DELTA   1e-3f

constexpr int D     = 256;
constexpr int K_TOT = 2048;

// A: 16 regions (as 0..7 head, 8..15 resid) x (128 rows x 4 chunks) slots:
//    halves addr = as*4096 + row*32 + q*8          (65536 halves = 128 KB)
// B: BB0 + buf*4096 + krow*32 + q*8                (2 x 8 KB, BK=32)
constexpr int BB0        = 65536;
constexpr int BBUF       = 4096;
constexpr int LDS_HALVES = BB0 + 2 * BBUF;     // 73728
constexpr int DYN_LDS    = LDS_HALVES * 2;     // 147456 bytes

typedef _Float16 half8v __attribute__((ext_vector_type(8)));
typedef _Float16 half4v __attribute__((ext_vector_type(4)));
typedef float    f32x4  __attribute__((ext_vector_type(4)));

// ---------------- prep: ec (half+residual) + esq + counter ----------------
__global__ void prep_kernel(const float* __restrict__ es,
                            const float* __restrict__ usage,
                            _Float16* __restrict__ ec,
                            float* __restrict__ esq,
                            int* __restrict__ counter) {
  const int bx   = blockIdx.x;
  const int t    = threadIdx.x;
  const int wid  = t >> 6;
  const int lane = t & 63;
  if (bx < K_TOT / 4) {
    const int k = bx * 4 + wid;
    const float u = fmaxf(usage[k], EPSILON);
    const float4 v = *(const float4*)(es + (size_t)k * D + lane * 4);
    float4 e;
    e.x = v.x / u; e.y = v.y / u; e.z = v.z / u; e.w = v.w / u;  // exact div
    half4v h, lo;
    h.x = (_Float16)e.x; lo.x = (_Float16)(e.x - (float)h.x);
    h.y = (_Float16)e.y; lo.y = (_Float16)(e.y - (float)h.y);
    h.z = (_Float16)e.z; lo.z = (_Float16)(e.z - (float)h.z);
    h.w = (_Float16)e.w; lo.w = (_Float16)(e.w - (float)h.w);
    *(half4v*)(ec + (size_t)k * 512 + lane * 4)       = h;
    *(half4v*)(ec + (size_t)k * 512 + 256 + lane * 4) = lo;
    float s = e.x * e.x + e.y * e.y + e.z * e.z + e.w * e.w;
    #pragma unroll
    for (int m = 1; m < 64; m <<= 1) s += __shfl_xor(s, m, 64);
    if (lane == 0) esq[k] = s;
  } else {
    if (t == 0) *counter = 0;
  }
}

// ---------------- A-resident MFMA distance GEMM + running top-2 ----------------
__global__ __launch_bounds__(512, 2)
void mm_kernel(const float* __restrict__ x, const _Float16* __restrict__ ec,
               const float* __restrict__ esq, float4* __restrict__ p4, int N) {
  extern __shared__ __align__(16) _Float16 lds[];
  const int t    = threadIdx.x;
  const int lane = t & 63;
  const int q    = lane >> 4;
  const int l15  = lane & 15;
  const int wid  = t >> 6;
  const int wn   = wid >> 1;            // 0..3 : 32-row group
  const int wk   = wid & 1;             // 0..1 : 64-col group
  const int n0   = blockIdx.x * 128;

  // ---- prologue: x fp32 -> f16 head|resid straight into A regions ----
  const int prow = t >> 2;              // 0..127
  const int pc   = t & 3;               // chunk (8 floats) 0..3
  #pragma unroll
  for (int i = 0; i < 8; ++i) {
    const float* src = x + (size_t)(n0 + prow) * D + i * 32 + pc * 8;
    const float4 f0 = *(const float4*)src;
    const float4 f1 = *(const float4*)(src + 4);
    const float f[8] = {f0.x, f0.y, f0.z, f0.w, f1.x, f1.y, f1.z, f1.w};
    half8v hv, lv;
    #pragma unroll
    for (int e = 0; e < 8; ++e) {
      const _Float16 h = (_Float16)f[e];
      hv[e] = h;
      lv[e] = (_Float16)(f[e] - (float)h);   // exact in fp32, then RN to f16
    }
    *(half8v*)&lds[i * 4096 + t * 8]       = hv;   // head region as=i
    *(half8v*)&lds[(i + 8) * 4096 + t * 8] = lv;   // resid region as=i+8
  }

  // B staging: thread t covers (row = t>>2, chunk = t&3); per-stage source
  // walks +32 halves (eh halves 0..255 then el halves 256..511: both linear).
  const _Float16* pB0 = ec + (size_t)prow * 512 + pc * 8;
  __builtin_amdgcn_global_load_lds(
      (const __attribute__((address_space(1))) void*)pB0,
      (__attribute__((address_space(3))) void*)&lds[BB0 + t * 8], 16, 0, 0);
  __syncthreads();

  // fragment half-offsets (loop-invariant); + mi*512 / + ni*512
  const int ah0 = (wn * 32 + l15) * 32 + q * 8;
  const int bh0 = (wk * 64 + l15) * 32 + q * 8;

  float rd0[2][4], rd1[2][4];
  int   ri0[2][4];
  #pragma unroll
  for (int mi = 0; mi < 2; ++mi)
    #pragma unroll
    for (int r = 0; r < 4; ++r) {
      rd0[mi][r] = FLT_MAX; rd1[mi][r] = FLT_MAX; ri0[mi][r] = 0x7fffffff;
    }

  int buf = 0;
  for (int kt = 0; kt < 16; ++kt) {
    const bool last_kt = (kt == 15);
    const _Float16* pk = pB0 + (size_t)kt * 65536;

    int   kc[4];
    float eqv[4];
    #pragma unroll
    for (int ni = 0; ni < 4; ++ni) {
      kc[ni]  = kt * 128 + wk * 64 + ni * 16 + l15;
      eqv[ni] = esq[kc[ni]];
    }

    f32x4 acc[2][4] = {};

    // ---- stages 0..7: B = eh[s]; MFMA xh*eh AND xl*eh (reuse staging) ----
    #pragma unroll
    for (int s = 0; s < 8; ++s) {
      __builtin_amdgcn_global_load_lds(
          (const __attribute__((address_space(1))) void*)(pk + (s + 1) * 32),
          (__attribute__((address_space(3))) void*)
              &lds[BB0 + (buf ^ 1) * BBUF + t * 8],
          16, 0, 0);
      half8v bf[4], ah[2], al[2];
      #pragma unroll
      for (int ni = 0; ni < 4; ++ni)
        bf[ni] = *(const half8v*)&lds[BB0 + buf * BBUF + bh0 + ni * 512];
      #pragma unroll
      for (int mi = 0; mi < 2; ++mi) {
        ah[mi] = *(const half8v*)&lds[s * 4096 + ah0 + mi * 512];
        al[mi] = *(const half8v*)&lds[(s + 8) * 4096 + ah0 + mi * 512];
      }
      #pragma unroll
      for (int mi = 0; mi < 2; ++mi)
        #pragma unroll
        for (int ni = 0; ni < 4; ++ni)
          acc[mi][ni] = __builtin_amdgcn_mfma_f32_16x16x32_f16(
              ah[mi], bf[ni], acc[mi][ni], 0, 0, 0);
      #pragma unroll
      for (int mi = 0; mi < 2; ++mi)
        #pragma unroll
        for (int ni = 0; ni < 4; ++ni)
          acc[mi][ni] = __builtin_amdgcn_mfma_f32_16x16x32_f16(
              al[mi], bf[ni], acc[mi][ni], 0, 0, 0);
      __syncthreads();
      buf ^= 1;
    }

    // ---- stages 8..15: B = el[s-8]; MFMA xh*el ----
    #pragma unroll
    for (int s = 8; s < 16; ++s) {
      if (!(last_kt && s == 15)) {
        const _Float16* np =
            (s == 15) ? (pB0 + (size_t)(kt + 1) * 65536) : (pk + (s + 1) * 32);
        __builtin_amdgcn_global_load_lds(
            (const __attribute__((address_space(1))) void*)np,
            (__attribute__((address_space(3))) void*)
                &lds[BB0 + (buf ^ 1) * BBUF + t * 8],
            16, 0, 0);
      }
      half8v bf[4], ah[2];
      #pragma unroll
      for (int ni = 0; ni < 4; ++ni)
        bf[ni] = *(const half8v*)&lds[BB0 + buf * BBUF + bh0 + ni * 512];
      #pragma unroll
      for (int mi = 0; mi < 2; ++mi)
        ah[mi] = *(const half8v*)&lds[(s - 8) * 4096 + ah0 + mi * 512];
      #pragma unroll
      for (int mi = 0; mi < 2; ++mi)
        #pragma unroll
        for (int ni = 0; ni < 4; ++ni)
          acc[mi][ni] = __builtin_amdgcn_mfma_f32_16x16x32_f16(
              ah[mi], bf[ni], acc[mi][ni], 0, 0, 0);
      __syncthreads();
      buf ^= 1;
    }

    // merge this k-tile into running top-2 (ascending k, strict '<')
    #pragma unroll
    for (int ni = 0; ni < 4; ++ni) {
      #pragma unroll
      for (int mi = 0; mi < 2; ++mi) {
        #pragma unroll
        for (int r = 0; r < 4; ++r) {
          const float d = fmaf(-2.f, acc[mi][ni][r], eqv[ni]);
          if (d < rd0[mi][r]) {
            rd1[mi][r] = rd0[mi][r]; rd0[mi][r] = d; ri0[mi][r] = kc[ni];
          } else {
            rd1[mi][r] = fminf(rd1[mi][r], d);
          }
        }
      }
    }
  }

  // cross-lane reduce over 16 k-cols; one p4 write per (row, wk)
  #pragma unroll
  for (int mi = 0; mi < 2; ++mi) {
    #pragma unroll
    for (int r = 0; r < 4; ++r) {
      float d0 = rd0[mi][r], d1 = rd1[mi][r];
      int   i0 = ri0[mi][r];
      #pragma unroll
      for (int off = 1; off < 16; off <<= 1) {
        const float od0 = __shfl_xor(d0, off, 16);
        const int   oi0 = __shfl_xor(i0, off, 16);
        const float od1 = __shfl_xor(d1, off, 16);
        if (od0 < d0 || (od0 == d0 && oi0 < i0)) {
          d1 = fminf(d0, od1); d0 = od0; i0 = oi0;
        } else {
          d1 = fminf(d1, od0);
        }
      }
      if (l15 == mi * 8 + r) {
        const int n = n0 + wn * 32 + mi * 16 + q * 4 + r;
        p4[(size_t)n * 2 + wk] = make_float4(d0, __int_as_float(i0), d1, 0.f);
      }
    }
  }
}

// ---------------- combine 2 partials + gather + flag ----------------
__global__ void combine_kernel(const float4* __restrict__ p4,
                               const float* __restrict__ es,
                               const float* __restrict__ usage,
                               float* __restrict__ out_q,
                               float* __restrict__ out_i,
                               int* __restrict__ list,
                               int* __restrict__ counter,
                               unsigned long long* __restrict__ rmin, int N) {
  const int wid  = threadIdx.x >> 6;
  const int lane = threadIdx.x & 63;
  const int n    = blockIdx.x * 4 + wid;

  float d0 = FLT_MAX, d1 = FLT_MAX;
  int   i0 = 0x7fffffff;
  if (lane < 2) {
    const float4 pv = p4[(size_t)n * 2 + lane];
    d0 = pv.x; i0 = __float_as_int(pv.y); d1 = pv.z;
  }
  {
    const float od0 = __shfl_xor(d0, 1, 2);
    const int   oi0 = __shfl_xor(i0, 1, 2);
    const float od1 = __shfl_xor(d1, 1, 2);
    if (od0 < d0 || (od0 == d0 && oi0 < i0)) {
      d1 = fminf(d0, od1); d0 = od0; i0 = oi0;
    } else {
      d1 = fminf(d1, od0);
    }
  }
  const int   idx = __shfl(i0, 0, 64);
  const float g0  = __shfl(d0, 0, 64);
  const float g1  = __shfl(d1, 0, 64);

  const float u = fmaxf(usage[idx], EPSILON);
  const float4 e = *(const float4*)(es + (size_t)idx * D + lane * 4);
  float4 qv;
  qv.x = e.x / u; qv.y = e.y / u; qv.z = e.z / u; qv.w = e.w / u;  // exact div
  *(float4*)(out_q + (size_t)n * D + lane * 4) = qv;
  if (lane == 0) {
    out_i[n] = (float)idx;
    if (g1 - g0 < DELTA) {
      rmin[n] = 0xFFFFFFFFFFFFFFFFull;
      const int pos = atomicAdd(counter, 1);
      list[pos] = n;
    }
  }
}

// ---------------- exact fp32 repair: 8 blocks per flagged row ----------------
__global__ void repair_kernel(const float* __restrict__ x,
                              const float* __restrict__ es,
                              const float* __restrict__ usage,
                              const float* __restrict__ esq,
                              const int* __restrict__ list,
                              const int* __restrict__ counter,
                              unsigned long long* __restrict__ rmin) {
  __shared__ float xs[256];
  const int t    = threadIdx.x;
  const int w    = t >> 6;
  const int lane = t & 63;
  const int cnt  = *counter;
  const int kseg = blockIdx.x & 7;

  for (int j = blockIdx.x >> 3; j < cnt; j += 256) {
    const int n = list[j];
    __syncthreads();
    xs[t] = x[(size_t)n * D + t];
    __syncthreads();
    const float4 xv = *(const float4*)&xs[lane * 4];

    float bd = FLT_MAX;
    int   bi = 0x7fffffff;
    const int kb0 = kseg * 256 + w * 64;
    for (int kk = 0; kk < 64; kk += 4) {
      const int kbase = kb0 + kk;
      float pd[4];
      #pragma unroll
      for (int j2 = 0; j2 < 4; ++j2) {
        const int k = kbase + j2;
        const float rs = 1.0f / fmaxf(usage[k], EPSILON);
        const float4 e = *(const float4*)(es + (size_t)k * D + lane * 4);
        float p = xv.x * (e.x * rs);
        p = fmaf(xv.y, e.y * rs, p);
        p = fmaf(xv.z, e.z * rs, p);
        pd[j2] = fmaf(xv.w, e.w * rs, p);
      }
      #pragma unroll
      for (int off = 1; off < 64; off <<= 1) {
        pd[0] += __shfl_xor(pd[0], off, 64);
        pd[1] += __shfl_xor(pd[1], off, 64);
        pd[2] += __shfl_xor(pd[2], off, 64);
        pd[3] += __shfl_xor(pd[3], off, 64);
      }
      #pragma unroll
      for (int j2 = 0; j2 < 4; ++j2) {
        const float dst = fmaf(-2.f, pd[j2], esq[kbase + j2]);
        if (dst < bd) { bd = dst; bi = kbase + j2; }
      }
    }
    if (lane == 0) {
      uint32_t ub = __float_as_uint(bd);
      ub = (ub & 0x80000000u) ? ~ub : (ub | 0x80000000u);
      const unsigned long long pk =
          ((unsigned long long)ub << 32) | (unsigned)bi;
      atomicMin(&rmin[n], pk);
    }
  }
}

// ---------------- repair pass 2: write repaired rows ----------------
__global__ void repair2_kernel(const float* __restrict__ es,
                               const float* __restrict__ usage,
                               const int* __restrict__ list,
                               const int* __restrict__ counter,
                               const unsigned long long* __restrict__ rmin,
                               float* __restrict__ out_q,
                               float* __restrict__ out_i) {
  const int t   = threadIdx.x;
  const int cnt = *counter;
  for (int j = blockIdx.x; j < cnt; j += 1024) {
    const int n   = list[j];
    const int idx = (int)(rmin[n] & 0x7fffffffu);
    const float u = fmaxf(usage[idx], EPSILON);
    out_q[(size_t)n * D + t] = es[(size_t)idx * D + t] / u;
    if (t == 0) out_i[n] = (float)idx;
  }
}

// ---------------- fallback path (R1, fp32 vector) ----------------
constexpr int TN = 128;
constexpr int DC = 32;
constexpr int KS = 2;
constexpr int RS = 196;

__global__ void esq_kernel(const float* __restrict__ es,
                           const float* __restrict__ usage,
                           float* __restrict__ esq) {
  const int lane = threadIdx.x & 63;
  const int w    = threadIdx.x >> 6;
  const int k    = blockIdx.x * 4 + w;
  const float u  = fmaxf(usage[k], EPSILON);
  const float4 e = *(const float4*)(es + (size_t)k * D + lane * 4);
  const float a = e.x / u, b = e.y / u, c = e.z / u, d = e.w / u;
  float s = a * a + b * b + c * c + d * d;
  #pragma unroll
  for (int m = 1; m < 64; m <<= 1) s += __shfl_xor(s, m, 64);
  if (lane == 0) esq[k] = s;
}

__global__ __launch_bounds__(256, 2)
void dist_kernel(const float* __restrict__ x,
                 const float* __restrict__ es,
                 const float* __restrict__ usage,
                 const float* __restrict__ esq,
                 float* __restrict__ bestd,
                 int* __restrict__ besti, int N) {
  __shared__ float smX[DC * RS];
  __shared__ float smE[DC * RS];
  const int t    = threadIdx.x;
  const int tx   = t & 15;
  const int ty   = t >> 4;
  const int n0   = blockIdx.x * TN;
  const int half = blockIdx.y;

  float best[8];
  int   bidx[8];
  #pragma unroll
  for (int i = 0; i < 8; ++i) { best[i] = FLT_MAX; bidx[i] = 0; }

  for (int kt = 0; kt < (K_TOT / KS) / 128; ++kt) {
    const int k0 = half * (K_TOT / KS) + kt * 128;
    float acc[8][8];
    #pragma unroll
    for (int i = 0; i < 8; ++i)
      #pragma unroll
      for (int j = 0; j < 8; ++j) acc[i][j] = 0.f;

    for (int dc = 0; dc < D; dc += DC) {
      __syncthreads();
      #pragma unroll
      for (int i = 0; i < 4; ++i) {
        const int f    = i * 256 + t;
        const int row  = f >> 3;
        const int c4   = f & 7;
        const int pcol = row + ((row >> 3) << 2);
        const float4 xv =
            *(const float4*)(x + (size_t)(n0 + row) * D + dc + c4 * 4);
        smX[(c4 * 4 + 0) * RS + pcol] = xv.x;
        smX[(c4 * 4 + 1) * RS + pcol] = xv.y;
        smX[(c4 * 4 + 2) * RS + pcol] = xv.z;
        smX[(c4 * 4 + 3) * RS + pcol] = xv.w;
        const int kk = k0 + row;
        const float rs = 1.0f / fmaxf(usage[kk], EPSILON);
        const float4 ev =
            *(const float4*)(es + (size_t)kk * D + dc + c4 * 4);
        smE[(c4 * 4 + 0) * RS + pcol] = ev.x * rs;
        smE[(c4 * 4 + 1) * RS + pcol] = ev.y * rs;
        smE[(c4 * 4 + 2) * RS + pcol] = ev.z * rs;
        smE[(c4 * 4 + 3) * RS + pcol] = ev.w * rs;
      }
      __syncthreads();
      #pragma unroll 4
      for (int d = 0; d < DC; ++d) {
        const float* px = &smX[d * RS + ty * 12];
        const float* pe = &smE[d * RS + tx * 12];
        const float4 xa = *(const float4*)px;
        const float4 xb = *(const float4*)(px + 4);
        const float4 ea = *(const float4*)pe;
        const float4 eb = *(const float4*)(pe + 4);
        const float xr[8] = {xa.x, xa.y, xa.z, xa.w, xb.x, xb.y, xb.z, xb.w};
        const float er[8] = {ea.x, ea.y, ea.z, ea.w, eb.x, eb.y, eb.z, eb.w};
        #pragma unroll
        for (int i = 0; i < 8; ++i)
          #pragma unroll
          for (int jj = 0; jj < 8; ++jj)
            acc[i][jj] = fmaf(xr[i], er[jj], acc[i][jj]);
      }
    }
    #pragma unroll
    for (int jj = 0; jj < 8; ++jj) {
      const int k = k0 + tx * 8 + jj;
      const float eq = esq[k];
      #pragma unroll
      for (int i = 0; i < 8; ++i) {
        const float dst = fmaf(-2.0f, acc[i][jj], eq);
        if (dst < best[i]) { best[i] = dst; bidx[i] = k; }
      }
    }
  }
  __syncthreads();
  float* rd = smX;
  int*   ri = (int*)smE;
  #pragma unroll
  for (int i = 0; i < 8; ++i) {
    const int r = ty * 8 + i;
    rd[tx * TN + r] = best[i];
    ri[tx * TN + r] = bidx[i];
  }
  __syncthreads();
  for (int off = 8; off >= 1; off >>= 1) {
    if (tx < off) {
      #pragma unroll
      for (int i = 0; i < 8; ++i) {
        const int r = ty * 8 + i;
        const float da = rd[tx * TN + r], db = rd[(tx + off) * TN + r];
        const int   ia = ri[tx * TN + r], ib = ri[(tx + off) * TN + r];
        if (db < da || (db == da && ib < ia)) {
          rd[tx * TN + r] = db;
          ri[tx * TN + r] = ib;
        }
      }
    }
    __syncthreads();
  }
  if (tx == 0) {
    #pragma unroll
    for (int i = 0; i < 8; ++i) {
      const int r = ty * 8 + i;
      bestd[(size_t)half * N + n0 + r] = rd[r];
      besti[(size_t)half * N + n0 + r] = ri[r];
    }
  }
}

__global__ void gather_kernel(const float* __restrict__ es,
                              const float* __restrict__ usage,
                              const float* __restrict__ bestd,
                              const int* __restrict__ besti,
                              float* __restrict__ out_q,
                              float* __restrict__ out_i, int N) {
  const int w    = threadIdx.x >> 6;
  const int lane = threadIdx.x & 63;
  const int n    = blockIdx.x * 4 + w;
  const float d0 = bestd[n];
  const float d1 = bestd[(size_t)N + n];
  const int   i0 = besti[n];
  const int   i1 = besti[(size_t)N + n];
  const int idx = (d1 < d0) ? i1 : i0;
  const float u = fmaxf(usage[idx], EPSILON);
  const float4 e = *(const float4*)(es + (size_t)idx * D + lane * 4);
  float4 qv;
  qv.x = e.x / u; qv.y = e.y / u; qv.z = e.z / u; qv.w = e.w / u;
  *(float4*)(out_q + (size_t)n * D + lane * 4) = qv;
  if (lane == 0) out_i[n] = (float)idx;
}

// ---------------- launch ----------------
extern "C" void kernel_launch(void* const* d_in, const int* in_sizes, int n_in,
                              void* d_out, int out_size, void* d_ws, size_t ws_size,
                              hipStream_t stream) {
  const float* x     = (const float*)d_in[0];  // [N, 256]
  const float* es    = (const float*)d_in[1];  // [2048, 256]
  const float* usage = (const float*)d_in[2];  // [2048]
  const int N = in_sizes[0] / D;               // 32768

  float* out_q = (float*)d_out;
  float* out_i = out_q + (size_t)N * D;

  const size_t EB = (size_t)K_TOT * 512 * 2;    // ec: 2 MB
  const size_t PB = (size_t)N * 2 * 16;         // p4: 1 MB
  const size_t off_p4   = EB;
  const size_t off_esq  = off_p4 + PB;
  const size_t off_list = off_esq + 8192;
  const size_t off_cnt  = off_list + (size_t)N * 4;
  const size_t off_rmin = off_cnt + 16;
  const size_t NEED     = off_rmin + (size_t)N * 8;

  char* wsb = (char*)d_ws;

  hipError_t attr_ok = hipFuncSetAttribute(
      (const void*)mm_kernel, hipFuncAttributeMaxDynamicSharedMemorySize,
      DYN_LDS);

  if (ws_size >= NEED && attr_ok == hipSuccess && (N % 128) == 0) {
    _Float16* ec   = (_Float16*)wsb;
    float4*   p4   = (float4*)(wsb + off_p4);
    float*    esq  = (float*)(wsb + off_esq);
    int*      list = (int*)(wsb + off_list);
    int*      cnt  = (int*)(wsb + off_cnt);
    unsigned long long* rmin = (unsigned long long*)(wsb + off_rmin);

    prep_kernel<<<K_TOT / 4 + 1, 256, 0, stream>>>(es, usage, ec, esq, cnt);
    mm_kernel<<<N / 128, 512, DYN_LDS, stream>>>(x, ec, esq, p4, N);
    combine_kernel<<<N / 4, 256, 0, stream>>>(p4, es, usage, out_q, out_i,
                                              list, cnt, rmin, N);
    repair_kernel<<<2048, 256, 0, stream>>>(x, es, usage, esq, list, cnt, rmin);
    repair2_kernel<<<1024, 256, 0, stream>>>(es, usage, list, cnt, rmin,
                                             out_q, out_i);
  } else {
    float* ws    = (float*)d_ws;
    float* esq   = ws;
    float* bestd = ws + K_TOT;
    int*   besti = (int*)(ws + K_TOT + (size_t)KS * N);
    esq_kernel<<<K_TOT / 4, 256, 0, stream>>>(es, usage, esq);
    dist_kernel<<<dim3(N / TN, KS), 256, 0, stream>>>(x, es, usage, esq,
                                                      bestd, besti, N);
    gather_kernel<<<N / 4, 256, 0, stream>>>(es, usage, bestd, besti,
                                             out_q, out_i, N);
  }
}

// Round 2
// 210.063 us; speedup vs baseline: 1.3741x; 1.0310x over previous
//
#include <hip/hip_runtime.h>
#include <float.h>
#include <stdint.h>

// MimiEuclideanCodebook: argmin_k ||x_n - e_k||^2 then gather e_k.
// R10 = R9 + (1) XOR bank-swizzle on all LDS fragment traffic (read addr +
// write addr for A, pre-swizzled global source for B since global_load_lds
// writes linearly), (2) A-head fragments hoisted to registers once (64 VGPR,
// A is k-invariant -> removes 2 of 6-8 LDS reads per stage), (3) combine
// kernel fused into mm epilogue via 4KB LDS exchange in the dead A region.
// Split-precision virtual K=768: xh*eh + xl*eh + xh*el. Top-2 carried in
// registers across k-tiles; exact-fp32 repair for rows with gap < DELTA.

#define EPSILON 1e-5f
#define DELTA   1e-3f

constexpr int D     = 256;
constexpr int K_TOT = 2048;

// A: 16 regions (as 0..7 head, 8..15 resid) x 4096 halves.
// B: BB0 + buf*4096 + region layout; regions are 512 halves (16 rows x 32).
// Swizzle (within 512-half region, 16B granules): g' = g ^ ((g>>3)&3).
constexpr int BB0        = 65536;
constexpr int BBUF       = 4096;
constexpr int LDS_HALVES = BB0 + 2 * BBUF;     // 73728
constexpr int DYN_LDS    = LDS_HALVES * 2;     // 147456 bytes

typedef _Float16 half8v __attribute__((ext_vector_type(8)));
typedef _Float16 half4v __attribute__((ext_vector_type(4)));
typedef float    f32x4  __attribute__((ext_vector_type(4)));

// ---------------- prep: ec (half+residual) + esq + counter ----------------
__global__ void prep_kernel(const float* __restrict__ es,
                            const float* __restrict__ usage,
                            _Float16* __restrict__ ec,
                            float* __restrict__ esq,
                            int* __restrict__ counter) {
  const int bx   = blockIdx.x;
  const int t    = threadIdx.x;
  const int wid  = t >> 6;
  const int lane = t & 63;
  if (bx < K_TOT / 4) {
    const int k = bx * 4 + wid;
    const float u = fmaxf(usage[k], EPSILON);
    const float4 v = *(const float4*)(es + (size_t)k * D + lane * 4);
    float4 e;
    e.x = v.x / u; e.y = v.y / u; e.z = v.z / u; e.w = v.w / u;  // exact div
    half4v h, lo;
    h.x = (_Float16)e.x; lo.x = (_Float16)(e.x - (float)h.x);
    h.y = (_Float16)e.y; lo.y = (_Float16)(e.y - (float)h.y);
    h.z = (_Float16)e.z; lo.z = (_Float16)(e.z - (float)h.z);
    h.w = (_Float16)e.w; lo.w = (_Float16)(e.w - (float)h.w);
    *(half4v*)(ec + (size_t)k * 512 + lane * 4)       = h;
    *(half4v*)(ec + (size_t)k * 512 + 256 + lane * 4) = lo;
    float s = e.x * e.x + e.y * e.y + e.z * e.z + e.w * e.w;
    #pragma unroll
    for (int m = 1; m < 64; m <<= 1) s += __shfl_xor(s, m, 64);
    if (lane == 0) esq[k] = s;
  } else {
    if (t == 0) *counter = 0;
  }
}

// ---------------- A-resident MFMA distance GEMM + top-2 + fused gather ----------------
__global__ __launch_bounds__(512, 2)
void mm_kernel(const float* __restrict__ x, const _Float16* __restrict__ ec,
               const float* __restrict__ esq, const float* __restrict__ es,
               const float* __restrict__ usage,
               float* __restrict__ out_q, float* __restrict__ out_i,
               int* __restrict__ list, int* __restrict__ counter,
               unsigned long long* __restrict__ rmin, int N) {
  extern __shared__ __align__(16) _Float16 lds[];
  const int t    = threadIdx.x;
  const int lane = t & 63;
  const int q    = lane >> 4;
  const int l15  = lane & 15;
  const int wid  = t >> 6;
  const int wn   = wid >> 1;            // 0..3 : 32-row group
  const int wk   = wid & 1;             // 0..1 : 64-col group
  const int n0   = blockIdx.x * 128;

  // ---- B staging source: pre-swizzled global address (rule #21) ----
  // Thread t writes LDS position p = t&63 of region t>>6 (linear DMA dest);
  // it must fetch the logical granule g = swz(p) = p ^ ((p>>3)&3).
  {
  }
  const int pgr  = t & 63;
  const int glog = pgr ^ ((pgr >> 3) & 3);
  const int brow = (t >> 6) * 16 + (glog >> 2);
  const int bch  = glog & 3;
  const _Float16* pB0 = ec + (size_t)brow * 512 + bch * 8;

  // issue stage-0 DMA first: overlaps with prologue conversion
  __builtin_amdgcn_global_load_lds(
      (const __attribute__((address_space(1))) void*)pB0,
      (__attribute__((address_space(3))) void*)&lds[BB0 + t * 8], 16, 0, 0);

  // ---- prologue: x fp32 -> f16 head|resid into swizzled A regions ----
  const int prow  = t >> 2;             // 0..127
  const int pc    = t & 3;              // chunk (8 floats) 0..3
  const int wbase = (t >> 6) * 512 + ((t & 63) ^ ((t >> 3) & 3)) * 8;
  #pragma unroll
  for (int i = 0; i < 8; ++i) {
    const float* src = x + (size_t)(n0 + prow) * D + i * 32 + pc * 8;
    const float4 f0 = *(const float4*)src;
    const float4 f1 = *(const float4*)(src + 4);
    const float f[8] = {f0.x, f0.y, f0.z, f0.w, f1.x, f1.y, f1.z, f1.w};
    half8v hv, lv;
    #pragma unroll
    for (int e = 0; e < 8; ++e) {
      const _Float16 h = (_Float16)f[e];
      hv[e] = h;
      lv[e] = (_Float16)(f[e] - (float)h);   // exact in fp32, then RN to f16
    }
    *(half8v*)&lds[i * 4096 + wbase]       = hv;   // head region as=i
    *(half8v*)&lds[(i + 8) * 4096 + wbase] = lv;   // resid region as=i+8
  }
  __syncthreads();

  // swizzled fragment position (halves) within a 512-half region
  const int gA = l15 * 4 + q;
  const int sp = (gA ^ ((l15 >> 1) & 3)) * 8;

  // ---- hoist A-head fragments to registers (k-invariant, 64 VGPR) ----
  half8v ahr[8][2];
  #pragma unroll
  for (int s = 0; s < 8; ++s)
    #pragma unroll
    for (int mi = 0; mi < 2; ++mi)
      ahr[s][mi] = *(const half8v*)&lds[s * 4096 + wn * 1024 + mi * 512 + sp];

  float rd0[2][4], rd1[2][4];
  int   ri0[2][4];
  #pragma unroll
  for (int mi = 0; mi < 2; ++mi)
    #pragma unroll
    for (int r = 0; r < 4; ++r) {
      rd0[mi][r] = FLT_MAX; rd1[mi][r] = FLT_MAX; ri0[mi][r] = 0x7fffffff;
    }

  int buf = 0;
  for (int kt = 0; kt < 16; ++kt) {
    const bool last_kt = (kt == 15);
    const _Float16* pk = pB0 + (size_t)kt * 65536;

    int   kc[4];
    float eqv[4];
    #pragma unroll
    for (int ni = 0; ni < 4; ++ni) {
      kc[ni]  = kt * 128 + wk * 64 + ni * 16 + l15;
      eqv[ni] = esq[kc[ni]];
    }

    f32x4 acc[2][4] = {};

    // 16 stages: s<8 -> B=eh[s], MFMA ah*eh + al*eh; s>=8 -> B=el, MFMA ah*el.
    #pragma unroll
    for (int s = 0; s < 16; ++s) {
      if (!(last_kt && s == 15)) {
        const _Float16* np =
            (s == 15) ? (pB0 + (size_t)(kt + 1) * 65536) : (pk + (s + 1) * 32);
        __builtin_amdgcn_global_load_lds(
            (const __attribute__((address_space(1))) void*)np,
            (__attribute__((address_space(3))) void*)
                &lds[BB0 + (buf ^ 1) * BBUF + t * 8],
            16, 0, 0);
      }
      half8v bf[4];
      #pragma unroll
      for (int ni = 0; ni < 4; ++ni)
        bf[ni] = *(const half8v*)
            &lds[BB0 + buf * BBUF + wk * 2048 + ni * 512 + sp];
      if (s < 8) {
        half8v al[2];
        #pragma unroll
        for (int mi = 0; mi < 2; ++mi)
          al[mi] = *(const half8v*)
              &lds[(s + 8) * 4096 + wn * 1024 + mi * 512 + sp];
        #pragma unroll
        for (int mi = 0; mi < 2; ++mi)
          #pragma unroll
          for (int ni = 0; ni < 4; ++ni)
            acc[mi][ni] = __builtin_amdgcn_mfma_f32_16x16x32_f16(
                ahr[s][mi], bf[ni], acc[mi][ni], 0, 0, 0);
        #pragma unroll
        for (int mi = 0; mi < 2; ++mi)
          #pragma unroll
          for (int ni = 0; ni < 4; ++ni)
            acc[mi][ni] = __builtin_amdgcn_mfma_f32_16x16x32_f16(
                al[mi], bf[ni], acc[mi][ni], 0, 0, 0);
      } else {
        #pragma unroll
        for (int mi = 0; mi < 2; ++mi)
          #pragma unroll
          for (int ni = 0; ni < 4; ++ni)
            acc[mi][ni] = __builtin_amdgcn_mfma_f32_16x16x32_f16(
                ahr[s - 8][mi], bf[ni], acc[mi][ni], 0, 0, 0);
      }
      __syncthreads();
      buf ^= 1;
    }

    // merge this k-tile into running top-2 (ascending k, strict '<')
    #pragma unroll
    for (int ni = 0; ni < 4; ++ni) {
      #pragma unroll
      for (int mi = 0; mi < 2; ++mi) {
        #pragma unroll
        for (int r = 0; r < 4; ++r) {
          const float d = fmaf(-2.f, acc[mi][ni][r], eqv[ni]);
          if (d < rd0[mi][r]) {
            rd1[mi][r] = rd0[mi][r]; rd0[mi][r] = d; ri0[mi][r] = kc[ni];
          } else {
            rd1[mi][r] = fminf(rd1[mi][r], d);
          }
        }
      }
    }
  }

  // cross-lane reduce over 16 k-cols; partials into LDS exchange (dead A head)
  float* ex = (float*)lds;   // [128 rows][2 wk][4 floats] = 4 KB
  #pragma unroll
  for (int mi = 0; mi < 2; ++mi) {
    #pragma unroll
    for (int r = 0; r < 4; ++r) {
      float d0 = rd0[mi][r], d1 = rd1[mi][r];
      int   i0 = ri0[mi][r];
      #pragma unroll
      for (int off = 1; off < 16; off <<= 1) {
        const float od0 = __shfl_xor(d0, off, 16);
        const int   oi0 = __shfl_xor(i0, off, 16);
        const float od1 = __shfl_xor(d1, off, 16);
        if (od0 < d0 || (od0 == d0 && oi0 < i0)) {
          d1 = fminf(d0, od1); d0 = od0; i0 = oi0;
        } else {
          d1 = fminf(d1, od0);
        }
      }
      if (l15 == mi * 8 + r) {
        const int row = wn * 32 + mi * 16 + q * 4 + r;   // 0..127
        *(float4*)&ex[(row * 2 + wk) * 4] =
            make_float4(d0, __int_as_float(i0), d1, 0.f);
      }
    }
  }
  __syncthreads();

  // fused combine + gather: 4 threads per row, 256B each (interleaved float4)
  {
    const int row = t >> 2;        // 0..127
    const int seg = t & 3;
    const float4 a = *(const float4*)&ex[(row * 2 + 0) * 4];
    const float4 b = *(const float4*)&ex[(row * 2 + 1) * 4];
    float d0, d1; int i0;
    const int ia = __float_as_int(a.y), ib = __float_as_int(b.y);
    if (b.x < a.x || (b.x == a.x && ib < ia)) {
      d0 = b.x; i0 = ib; d1 = fminf(a.x, b.z);
    } else {
      d0 = a.x; i0 = ia; d1 = fminf(a.z, b.x);
    }
    const int n = n0 + row;
    const float u  = fmaxf(usage[i0], EPSILON);
    const float4* src = (const float4*)(es + (size_t)i0 * D);
    float4*       dst = (float4*)(out_q + (size_t)n * D);
    #pragma unroll
    for (int i = 0; i < 16; ++i) {
      const int j = i * 4 + seg;
      const float4 e = src[j];
      dst[j] = make_float4(e.x / u, e.y / u, e.z / u, e.w / u);  // exact div
    }
    if (seg == 0) {
      out_i[n] = (float)i0;
      if (d1 - d0 < DELTA) {
        rmin[n] = 0xFFFFFFFFFFFFFFFFull;
        const int pos = atomicAdd(counter, 1);
        list[pos] = n;
      }
    }
  }
}

// ---------------- exact fp32 repair: 8 blocks per flagged row ----------------
__global__ void repair_kernel(const float* __restrict__ x,
                              const float* __restrict__ es,
                              const float* __restrict__ usage,
                              const float* __restrict__ esq,
                              const int* __restrict__ list,
                              const int* __restrict__ counter,
                              unsigned long long* __restrict__ rmin) {
  __shared__ float xs[256];
  const int t    = threadIdx.x;
  const int w    = t >> 6;
  const int lane = t & 63;
  const int cnt  = *counter;
  const int kseg = blockIdx.x & 7;

  for (int j = blockIdx.x >> 3; j < cnt; j += 256) {
    const int n = list[j];
    __syncthreads();
    xs[t] = x[(size_t)n * D + t];
    __syncthreads();
    const float4 xv = *(const float4*)&xs[lane * 4];

    float bd = FLT_MAX;
    int   bi = 0x7fffffff;
    const int kb0 = kseg * 256 + w * 64;
    for (int kk = 0; kk < 64; kk += 4) {
      const int kbase = kb0 + kk;
      float pd[4];
      #pragma unroll
      for (int j2 = 0; j2 < 4; ++j2) {
        const int k = kbase + j2;
        const float rs = 1.0f / fmaxf(usage[k], EPSILON);
        const float4 e = *(const float4*)(es + (size_t)k * D + lane * 4);
        float p = xv.x * (e.x * rs);
        p = fmaf(xv.y, e.y * rs, p);
        p = fmaf(xv.z, e.z * rs, p);
        pd[j2] = fmaf(xv.w, e.w * rs, p);
      }
      #pragma unroll
      for (int off = 1; off < 64; off <<= 1) {
        pd[0] += __shfl_xor(pd[0], off, 64);
        pd[1] += __shfl_xor(pd[1], off, 64);
        pd[2] += __shfl_xor(pd[2], off, 64);
        pd[3] += __shfl_xor(pd[3], off, 64);
      }
      #pragma unroll
      for (int j2 = 0; j2 < 4; ++j2) {
        const float dst = fmaf(-2.f, pd[j2], esq[kbase + j2]);
        if (dst < bd) { bd = dst; bi = kbase + j2; }
      }
    }
    if (lane == 0) {
      uint32_t ub = __float_as_uint(bd);
      ub = (ub & 0x80000000u) ? ~ub : (ub | 0x80000000u);
      const unsigned long long pk =
          ((unsigned long long)ub << 32) | (unsigned)bi;
      atomicMin(&rmin[n], pk);
    }
  }
}

// ---------------- repair pass 2: write repaired rows ----------------
__global__ void repair2_kernel(const float* __restrict__ es,
                               const float* __restrict__ usage,
                               const int* __restrict__ list,
                               const int* __restrict__ counter,
                               const unsigned long long* __restrict__ rmin,
                               float* __restrict__ out_q,
                               float* __restrict__ out_i) {
  const int t   = threadIdx.x;
  const int cnt = *counter;
  for (int j = blockIdx.x; j < cnt; j += 1024) {
    const int n   = list[j];
    const int idx = (int)(rmin[n] & 0x7fffffffu);
    const float u = fmaxf(usage[idx], EPSILON);
    out_q[(size_t)n * D + t] = es[(size_t)idx * D + t] / u;
    if (t == 0) out_i[n] = (float)idx;
  }
}

// ---------------- fallback path (R1, fp32 vector) ----------------
constexpr int TN = 128;
constexpr int DC = 32;
constexpr int KS = 2;
constexpr int RS = 196;

__global__ void esq_kernel(const float* __restrict__ es,
                           const float* __restrict__ usage,
                           float* __restrict__ esq) {
  const int lane = threadIdx.x & 63;
  const int w    = threadIdx.x >> 6;
  const int k    = blockIdx.x * 4 + w;
  const float u  = fmaxf(usage[k], EPSILON);
  const float4 e = *(const float4*)(es + (size_t)k * D + lane * 4);
  const float a = e.x / u, b = e.y / u, c = e.z / u, d = e.w / u;
  float s = a * a + b * b + c * c + d * d;
  #pragma unroll
  for (int m = 1; m < 64; m <<= 1) s += __shfl_xor(s, m, 64);
  if (lane == 0) esq[k] = s;
}

__global__ __launch_bounds__(256, 2)
void dist_kernel(const float* __restrict__ x,
                 const float* __restrict__ es,
                 const float* __restrict__ usage,
                 const float* __restrict__ esq,
                 float* __restrict__ bestd,
                 int* __restrict__ besti, int N) {
  __shared__ float smX[DC * RS];
  __shared__ float smE[DC * RS];
  const int t    = threadIdx.x;
  const int tx   = t & 15;
  const int ty   = t >> 4;
  const int n0   = blockIdx.x * TN;
  const int half = blockIdx.y;

  float best[8];
  int   bidx[8];
  #pragma unroll
  for (int i = 0; i < 8; ++i) { best[i] = FLT_MAX; bidx[i] = 0; }

  for (int kt = 0; kt < (K_TOT / KS) / 128; ++kt) {
    const int k0 = half * (K_TOT / KS) + kt * 128;
    float acc[8][8];
    #pragma unroll
    for (int i = 0; i < 8; ++i)
      #pragma unroll
      for (int j = 0; j < 8; ++j) acc[i][j] = 0.f;

    for (int dc = 0; dc < D; dc += DC) {
      __syncthreads();
      #pragma unroll
      for (int i = 0; i < 4; ++i) {
        const int f    = i * 256 + t;
        const int row  = f >> 3;
        const int c4   = f & 7;
        const int pcol = row + ((row >> 3) << 2);
        const float4 xv =
            *(const float4*)(x + (size_t)(n0 + row) * D + dc + c4 * 4);
        smX[(c4 * 4 + 0) * RS + pcol] = xv.x;
        smX[(c4 * 4 + 1) * RS + pcol] = xv.y;
        smX[(c4 * 4 + 2) * RS + pcol] = xv.z;
        smX[(c4 * 4 + 3) * RS + pcol] = xv.w;
        const int kk = k0 + row;
        const float rs = 1.0f / fmaxf(usage[kk], EPSILON);
        const float4 ev =
            *(const float4*)(es + (size_t)kk * D + dc + c4 * 4);
        smE[(c4 * 4 + 0) * RS + pcol] = ev.x * rs;
        smE[(c4 * 4 + 1) * RS + pcol] = ev.y * rs;
        smE[(c4 * 4 + 2) * RS + pcol] = ev.z * rs;
        smE[(c4 * 4 + 3) * RS + pcol] = ev.w * rs;
      }
      __syncthreads();
      #pragma unroll 4
      for (int d = 0; d < DC; ++d) {
        const float* px = &smX[d * RS + ty * 12];
        const float* pe = &smE[d * RS + tx * 12];
        const float4 xa = *(const float4*)px;
        const float4 xb = *(const float4*)(px + 4);
        const float4 ea = *(const float4*)pe;
        const float4 eb = *(const float4*)(pe + 4);
        const float xr[8] = {xa.x, xa.y, xa.z, xa.w, xb.x, xb.y, xb.z, xb.w};
        const float er[8] = {ea.x, ea.y, ea.z, ea.w, eb.x, eb.y, eb.z, eb.w};
        #pragma unroll
        for (int i = 0; i < 8; ++i)
          #pragma unroll
          for (int jj = 0; jj < 8; ++jj)
            acc[i][jj] = fmaf(xr[i], er[jj], acc[i][jj]);
      }
    }
    #pragma unroll
    for (int jj = 0; jj < 8; ++jj) {
      const int k = k0 + tx * 8 + jj;
      const float eq = esq[k];
      #pragma unroll
      for (int i = 0; i < 8; ++i) {
        const float dst = fmaf(-2.0f, acc[i][jj], eq);
        if (dst < best[i]) { best[i] = dst; bidx[i] = k; }
      }
    }
  }
  __syncthreads();
  float* rd = smX;
  int*   ri = (int*)smE;
  #pragma unroll
  for (int i = 0; i < 8; ++i) {
    const int r = ty * 8 + i;
    rd[tx * TN + r] = best[i];
    ri[tx * TN + r] = bidx[i];
  }
  __syncthreads();
  for (int off = 8; off >= 1; off >>= 1) {
    if (tx < off) {
      #pragma unroll
      for (int i = 0; i < 8; ++i) {
        const int r = ty * 8 + i;
        const float da = rd[tx * TN + r], db = rd[(tx + off) * TN + r];
        const int   ia = ri[tx * TN + r], ib = ri[(tx + off) * TN + r];
        if (db < da || (db == da && ib < ia)) {
          rd[tx * TN + r] = db;
          ri[tx * TN + r] = ib;
        }
      }
    }
    __syncthreads();
  }
  if (tx == 0) {
    #pragma unroll
    for (int i = 0; i < 8; ++i) {
      const int r = ty * 8 + i;
      bestd[(size_t)half * N + n0 + r] = rd[r];
      besti[(size_t)half * N + n0 + r] = ri[r];
    }
  }
}

__global__ void gather_kernel(const float* __restrict__ es,
                              const float* __restrict__ usage,
                              const float* __restrict__ bestd,
                              const int* __restrict__ besti,
                              float* __restrict__ out_q,
                              float* __restrict__ out_i, int N) {
  const int w    = threadIdx.x >> 6;
  const int lane = threadIdx.x & 63;
  const int n    = blockIdx.x * 4 + w;
  const float d0 = bestd[n];
  const float d1 = bestd[(size_t)N + n];
  const int   i0 = besti[n];
  const int   i1 = besti[(size_t)N + n];
  const int idx = (d1 < d0) ? i1 : i0;
  const float u = fmaxf(usage[idx], EPSILON);
  const float4 e = *(const float4*)(es + (size_t)idx * D + lane * 4);
  float4 qv;
  qv.x = e.x / u; qv.y = e.y / u; qv.z = e.z / u; qv.w = e.w / u;
  *(float4*)(out_q + (size_t)n * D + lane * 4) = qv;
  if (lane == 0) out_i[n] = (float)idx;
}

// ---------------- launch ----------------
extern "C" void kernel_launch(void* const* d_in, const int* in_sizes, int n_in,
                              void* d_out, int out_size, void* d_ws, size_t ws_size,
                              hipStream_t stream) {
  const float* x     = (const float*)d_in[0];  // [N, 256]
  const float* es    = (const float*)d_in[1];  // [2048, 256]
  const float* usage = (const float*)d_in[2];  // [2048]
  const int N = in_sizes[0] / D;               // 32768

  float* out_q = (float*)d_out;
  float* out_i = out_q + (size_t)N * D;

  const size_t EB = (size_t)K_TOT * 512 * 2;    // ec: 2 MB
  const size_t off_esq  = EB;
  const size_t off_list = off_esq + 8192;
  const size_t off_cnt  = off_list + (size_t)N * 4;
  const size_t off_rmin = off_cnt + 16;
  const size_t NEED     = off_rmin + (size_t)N * 8;

  char* wsb = (char*)d_ws;

  hipError_t attr_ok = hipFuncSetAttribute(
      (const void*)mm_kernel, hipFuncAttributeMaxDynamicSharedMemorySize,
      DYN_LDS);

  if (ws_size >= NEED && attr_ok == hipSuccess && (N % 128) == 0) {
    _Float16* ec   = (_Float16*)wsb;
    float*    esq  = (float*)(wsb + off_esq);
    int*      list = (int*)(wsb + off_list);
    int*      cnt  = (int*)(wsb + off_cnt);
    unsigned long long* rmin = (unsigned long long*)(wsb + off_rmin);

    prep_kernel<<<K_TOT / 4 + 1, 256, 0, stream>>>(es, usage, ec, esq, cnt);
    mm_kernel<<<N / 128, 512, DYN_LDS, stream>>>(x, ec, esq, es, usage,
                                                 out_q, out_i, list, cnt,
                                                 rmin, N);
    repair_kernel<<<2048, 256, 0, stream>>>(x, es, usage, esq, list, cnt, rmin);
    repair2_kernel<<<1024, 256, 0, stream>>>(es, usage, list, cnt, rmin,
                                             out_q, out_i);
  } else {
    float* ws    = (float*)d_ws;
    float* esq   = ws;
    float* bestd = ws + K_TOT;
    int*   besti = (int*)(ws + K_TOT + (size_t)KS * N);
    esq_kernel<<<K_TOT / 4, 256, 0, stream>>>(es, usage, esq);
    dist_kernel<<<dim3(N / TN, KS), 256, 0, stream>>>(x, es, usage, esq,
                                                      bestd, besti, N);
    gather_kernel<<<N / 4, 256, 0, stream>>>(es, usage, bestd, besti,
                                             out_q, out_i, N);
  }
}

// Round 3
// 187.182 us; speedup vs baseline: 1.5421x; 1.1222x over previous
//
#include <hip/hip_runtime.h>
#include <float.h>
#include <stdint.h>

// MimiEuclideanCodebook: argmin_k ||x_n - e_k||^2 then gather e_k.
// R11 = counted-vmcnt pipeline (T3+T4): raw s_barrier + asm s_waitcnt vmcnt(N),
// 4 B-buffers, prefetch depth 3, BK=64 (128 stages instead of 256).
// LDS refit: A-head regions (64KB) die after register hoist -> B buffers live
// there; resid regions persist at 64..128KB; esq staged to LDS (8KB) so the
// k-tile loop has ZERO non-DMA vmem (keeps the vmcnt count exact).
// B swizzle for [128]x[64h] stage: granule g -> g ^ ((g>>3)&7) (involution),
// pre-swizzled global source + XOR'd read addr (rule #21). setprio around MFMA.
// Split-precision virtual K=768: xh*eh + xl*eh + xh*el. Top-2 in registers;
// exact-fp32 repair for rows with gap < DELTA. Fused combine+gather epilogue.

#define EPSILON 1e-5f
#define DELTA   1e-3f

constexpr int D     = 256;
constexpr int K_TOT = 2048;

// LDS map (halves):
//   0..32768    : prologue A-head regions (8 x 4096); after hoist: B bufs 4 x 8192
//   32768..65536: A-resid regions (8 x 4096), persist through main loop
//   65536..69632: esq copy (2048 floats)
constexpr int RES_H      = 32768;
constexpr int ESQ_H      = 65536;
constexpr int LDS_HALVES = 69632;
constexpr int DYN_LDS    = LDS_HALVES * 2;     // 139264 bytes

typedef _Float16 half8v __attribute__((ext_vector_type(8)));
typedef _Float16 half4v __attribute__((ext_vector_type(4)));
typedef float    f32x4  __attribute__((ext_vector_type(4)));

#define GLL(SRC, DST)                                                   \
  __builtin_amdgcn_global_load_lds(                                     \
      (const __attribute__((address_space(1))) void*)(SRC),             \
      (__attribute__((address_space(3))) void*)(DST), 16, 0, 0)

// ---------------- prep: ec (half+residual) + esq + counter ----------------
__global__ void prep_kernel(const float* __restrict__ es,
                            const float* __restrict__ usage,
                            _Float16* __restrict__ ec,
                            float* __restrict__ esq,
                            int* __restrict__ counter) {
  const int bx   = blockIdx.x;
  const int t    = threadIdx.x;
  const int wid  = t >> 6;
  const int lane = t & 63;
  if (bx < K_TOT / 4) {
    const int k = bx * 4 + wid;
    const float u = fmaxf(usage[k], EPSILON);
    const float4 v = *(const float4*)(es + (size_t)k * D + lane * 4);
    float4 e;
    e.x = v.x / u; e.y = v.y / u; e.z = v.z / u; e.w = v.w / u;  // exact div
    half4v h, lo;
    h.x = (_Float16)e.x; lo.x = (_Float16)(e.x - (float)h.x);
    h.y = (_Float16)e.y; lo.y = (_Float16)(e.y - (float)h.y);
    h.z = (_Float16)e.z; lo.z = (_Float16)(e.z - (float)h.z);
    h.w = (_Float16)e.w; lo.w = (_Float16)(e.w - (float)h.w);
    *(half4v*)(ec + (size_t)k * 512 + lane * 4)       = h;
    *(half4v*)(ec + (size_t)k * 512 + 256 + lane * 4) = lo;
    float s = e.x * e.x + e.y * e.y + e.z * e.z + e.w * e.w;
    #pragma unroll
    for (int m = 1; m < 64; m <<= 1) s += __shfl_xor(s, m, 64);
    if (lane == 0) esq[k] = s;
  } else {
    if (t == 0) *counter = 0;
  }
}

// ---------------- A-resident MFMA distance GEMM + top-2 + fused gather ----------------
__global__ __launch_bounds__(512, 2)
void mm_kernel(const float* __restrict__ x, const _Float16* __restrict__ ec,
               const float* __restrict__ esq, const float* __restrict__ es,
               const float* __restrict__ usage,
               float* __restrict__ out_q, float* __restrict__ out_i,
               int* __restrict__ list, int* __restrict__ counter,
               unsigned long long* __restrict__ rmin, int N) {
  extern __shared__ __align__(16) _Float16 lds[];
  const int t    = threadIdx.x;
  const int lane = t & 63;
  const int q    = lane >> 4;
  const int l15  = lane & 15;
  const int wid  = t >> 6;
  const int wn   = wid >> 1;            // 0..3 : 32-row group
  const int wk   = wid & 1;             // 0..1 : 64-col group
  const int n0   = blockIdx.x * 128;

  // ---- esq -> LDS copy (never rewritten; keeps k-tile loop vmem-free) ----
  float* esq_lds = (float*)&lds[ESQ_H];
  {
    const float4 ev = *(const float4*)(esq + t * 4);
    *(float4*)&esq_lds[t * 4] = ev;
  }

  // ---- prologue: x fp32 -> f16 head|resid into swizzled A regions ----
  const int prow  = t >> 2;             // 0..127
  const int pc    = t & 3;              // chunk (8 floats) 0..3
  const int wbase = (t >> 6) * 512 + ((t & 63) ^ ((t >> 3) & 3)) * 8;
  #pragma unroll
  for (int i = 0; i < 8; ++i) {
    const float* src = x + (size_t)(n0 + prow) * D + i * 32 + pc * 8;
    const float4 f0 = *(const float4*)src;
    const float4 f1 = *(const float4*)(src + 4);
    const float f[8] = {f0.x, f0.y, f0.z, f0.w, f1.x, f1.y, f1.z, f1.w};
    half8v hv, lv;
    #pragma unroll
    for (int e = 0; e < 8; ++e) {
      const _Float16 h = (_Float16)f[e];
      hv[e] = h;
      lv[e] = (_Float16)(f[e] - (float)h);   // exact in fp32, then RN to f16
    }
    *(half8v*)&lds[i * 4096 + wbase]         = hv;   // head region (dies)
    *(half8v*)&lds[RES_H + i * 4096 + wbase] = lv;   // resid region (persists)
  }
  __syncthreads();

  // swizzled fragment position (halves) within a 512-half region
  const int gA = l15 * 4 + q;
  const int sp = (gA ^ ((l15 >> 1) & 3)) * 8;

  // ---- hoist A-head fragments to registers (k-invariant, 64 VGPR) ----
  half8v ahr[8][2];
  #pragma unroll
  for (int s = 0; s < 8; ++s)
    #pragma unroll
    for (int mi = 0; mi < 2; ++mi)
      ahr[s][mi] = *(const half8v*)&lds[s * 4096 + wn * 1024 + mi * 512 + sp];
  __syncthreads();   // all waves done with head regions -> B bufs may reuse

  // ---- B staging descriptor: pre-swizzled global source ----
  // Physical slot p = i*512+t holds logical granule (row = p>>3, c = (p&7)^(row&7)).
  const int r0 = t >> 3;                       // rows 0..63 (instr1: +64)
  const int cl = (t & 7) ^ (r0 & 7);
  const _Float16* pB = ec + (size_t)r0 * 512 + cl * 8;

  // prologue DMAs: stages 0,1,2 into bufs 0,1,2
  #pragma unroll
  for (int s = 0; s < 3; ++s) {
    const _Float16* sp0 = pB + s * 64;
    GLL(sp0,         &lds[s * 8192 + t * 8]);
    GLL(sp0 + 32768, &lds[s * 8192 + 4096 + t * 8]);
  }

  // fragment read offsets (halves): row*64 + ((j*4+q)^(l15&7))*16B-granule
  int bfoff[4][2];
  #pragma unroll
  for (int ni = 0; ni < 4; ++ni)
    #pragma unroll
    for (int j = 0; j < 2; ++j)
      bfoff[ni][j] = (wk * 64 + ni * 16 + l15) * 64 +
                     (((j << 2) + q) ^ (l15 & 7)) * 8;

  float rd0[2][4], rd1[2][4];
  int   ri0[2][4];
  #pragma unroll
  for (int mi = 0; mi < 2; ++mi)
    #pragma unroll
    for (int r = 0; r < 4; ++r) {
      rd0[mi][r] = FLT_MAX; rd1[mi][r] = FLT_MAX; ri0[mi][r] = 0x7fffffff;
    }

  for (int kt = 0; kt < 16; ++kt) {
    int   kc[4];
    float eqv[4];
    #pragma unroll
    for (int ni = 0; ni < 4; ++ni) {
      kc[ni]  = kt * 128 + wk * 64 + ni * 16 + l15;
      eqv[ni] = esq_lds[kc[ni]];
    }

    f32x4 acc[2][4] = {};

    // 8 stages of BK=64: sidx<4 -> B=eh, MFMA ah+al; sidx>=4 -> B=el, MFMA ah.
    #pragma unroll
    for (int sidx = 0; sidx < 8; ++sidx) {
      const int ss = kt * 8 + sidx;
      // counted wait: stage-ss loads retired; 2 newer stages stay in flight
      if (kt == 15 && sidx == 6)
        asm volatile("s_waitcnt vmcnt(2)" ::: "memory");
      else if (kt == 15 && sidx == 7)
        asm volatile("s_waitcnt vmcnt(0)" ::: "memory");
      else
        asm volatile("s_waitcnt vmcnt(4)" ::: "memory");
      __builtin_amdgcn_s_barrier();
      __builtin_amdgcn_sched_barrier(0);

      // prefetch stage ss+3 into buf (ss+3)&3 (that buf was consumed at ss-1)
      if (!(kt == 15 && sidx >= 5)) {
        const int ns = ss + 3;
        const _Float16* np = pB + (size_t)(ns >> 3) * 65536 + (ns & 7) * 64;
        const int nb = (ns & 3) * 8192;
        GLL(np,         &lds[nb + t * 8]);
        GLL(np + 32768, &lds[nb + 4096 + t * 8]);
      }

      const int bb = (ss & 3) * 8192;
      __builtin_amdgcn_s_setprio(1);
      #pragma unroll
      for (int j = 0; j < 2; ++j) {
        half8v bf[4];
        #pragma unroll
        for (int ni = 0; ni < 4; ++ni)
          bf[ni] = *(const half8v*)&lds[bb + bfoff[ni][j]];
        const int ks = (sidx & 3) * 2 + j;      // A k-step 0..7
        if (sidx < 4) {
          half8v al[2];
          #pragma unroll
          for (int mi = 0; mi < 2; ++mi)
            al[mi] = *(const half8v*)
                &lds[RES_H + ks * 4096 + wn * 1024 + mi * 512 + sp];
          #pragma unroll
          for (int mi = 0; mi < 2; ++mi)
            #pragma unroll
            for (int ni = 0; ni < 4; ++ni)
              acc[mi][ni] = __builtin_amdgcn_mfma_f32_16x16x32_f16(
                  ahr[ks][mi], bf[ni], acc[mi][ni], 0, 0, 0);
          #pragma unroll
          for (int mi = 0; mi < 2; ++mi)
            #pragma unroll
            for (int ni = 0; ni < 4; ++ni)
              acc[mi][ni] = __builtin_amdgcn_mfma_f32_16x16x32_f16(
                  al[mi], bf[ni], acc[mi][ni], 0, 0, 0);
        } else {
          #pragma unroll
          for (int mi = 0; mi < 2; ++mi)
            #pragma unroll
            for (int ni = 0; ni < 4; ++ni)
              acc[mi][ni] = __builtin_amdgcn_mfma_f32_16x16x32_f16(
                  ahr[ks][mi], bf[ni], acc[mi][ni], 0, 0, 0);
        }
      }
      __builtin_amdgcn_s_setprio(0);
    }

    // merge this k-tile into running top-2 (ascending k, strict '<')
    #pragma unroll
    for (int ni = 0; ni < 4; ++ni) {
      #pragma unroll
      for (int mi = 0; mi < 2; ++mi) {
        #pragma unroll
        for (int r = 0; r < 4; ++r) {
          const float d = fmaf(-2.f, acc[mi][ni][r], eqv[ni]);
          if (d < rd0[mi][r]) {
            rd1[mi][r] = rd0[mi][r]; rd0[mi][r] = d; ri0[mi][r] = kc[ni];
          } else {
            rd1[mi][r] = fminf(rd1[mi][r], d);
          }
        }
      }
    }
  }
  __syncthreads();   // loop fully drained; B-buf space reusable as exchange

  // cross-lane reduce over 16 k-cols; partials into LDS exchange
  float* ex = (float*)lds;   // [128 rows][2 wk][4 floats] = 4 KB
  #pragma unroll
  for (int mi = 0; mi < 2; ++mi) {
    #pragma unroll
    for (int r = 0; r < 4; ++r) {
      float d0 = rd0[mi][r], d1 = rd1[mi][r];
      int   i0 = ri0[mi][r];
      #pragma unroll
      for (int off = 1; off < 16; off <<= 1) {
        const float od0 = __shfl_xor(d0, off, 16);
        const int   oi0 = __shfl_xor(i0, off, 16);
        const float od1 = __shfl_xor(d1, off, 16);
        if (od0 < d0 || (od0 == d0 && oi0 < i0)) {
          d1 = fminf(d0, od1); d0 = od0; i0 = oi0;
        } else {
          d1 = fminf(d1, od0);
        }
      }
      if (l15 == mi * 8 + r) {
        const int row = wn * 32 + mi * 16 + q * 4 + r;   // 0..127
        *(float4*)&ex[(row * 2 + wk) * 4] =
            make_float4(d0, __int_as_float(i0), d1, 0.f);
      }
    }
  }
  __syncthreads();

  // fused combine + gather: 4 threads per row, 256B each (interleaved float4)
  {
    const int row = t >> 2;        // 0..127
    const int seg = t & 3;
    const float4 a = *(const float4*)&ex[(row * 2 + 0) * 4];
    const float4 b = *(const float4*)&ex[(row * 2 + 1) * 4];
    float d0, d1; int i0;
    const int ia = __float_as_int(a.y), ib = __float_as_int(b.y);
    if (b.x < a.x || (b.x == a.x && ib < ia)) {
      d0 = b.x; i0 = ib; d1 = fminf(a.x, b.z);
    } else {
      d0 = a.x; i0 = ia; d1 = fminf(a.z, b.x);
    }
    const int n = n0 + row;
    const float u  = fmaxf(usage[i0], EPSILON);
    const float4* src = (const float4*)(es + (size_t)i0 * D);
    float4*       dst = (float4*)(out_q + (size_t)n * D);
    #pragma unroll
    for (int i = 0; i < 16; ++i) {
      const int j = i * 4 + seg;
      const float4 e = src[j];
      dst[j] = make_float4(e.x / u, e.y / u, e.z / u, e.w / u);  // exact div
    }
    if (seg == 0) {
      out_i[n] = (float)i0;
      if (d1 - d0 < DELTA) {
        rmin[n] = 0xFFFFFFFFFFFFFFFFull;
        const int pos = atomicAdd(counter, 1);
        list[pos] = n;
      }
    }
  }
}

// ---------------- exact fp32 repair: 8 blocks per flagged row ----------------
__global__ void repair_kernel(const float* __restrict__ x,
                              const float* __restrict__ es,
                              const float* __restrict__ usage,
                              const float* __restrict__ esq,
                              const int* __restrict__ list,
                              const int* __restrict__ counter,
                              unsigned long long* __restrict__ rmin) {
  __shared__ float xs[256];
  const int t    = threadIdx.x;
  const int w    = t >> 6;
  const int lane = t & 63;
  const int cnt  = *counter;
  const int kseg = blockIdx.x & 7;

  for (int j = blockIdx.x >> 3; j < cnt; j += 256) {
    const int n = list[j];
    __syncthreads();
    xs[t] = x[(size_t)n * D + t];
    __syncthreads();
    const float4 xv = *(const float4*)&xs[lane * 4];

    float bd = FLT_MAX;
    int   bi = 0x7fffffff;
    const int kb0 = kseg * 256 + w * 64;
    for (int kk = 0; kk < 64; kk += 4) {
      const int kbase = kb0 + kk;
      float pd[4];
      #pragma unroll
      for (int j2 = 0; j2 < 4; ++j2) {
        const int k = kbase + j2;
        const float rs = 1.0f / fmaxf(usage[k], EPSILON);
        const float4 e = *(const float4*)(es + (size_t)k * D + lane * 4);
        float p = xv.x * (e.x * rs);
        p = fmaf(xv.y, e.y * rs, p);
        p = fmaf(xv.z, e.z * rs, p);
        pd[j2] = fmaf(xv.w, e.w * rs, p);
      }
      #pragma unroll
      for (int off = 1; off < 64; off <<= 1) {
        pd[0] += __shfl_xor(pd[0], off, 64);
        pd[1] += __shfl_xor(pd[1], off, 64);
        pd[2] += __shfl_xor(pd[2], off, 64);
        pd[3] += __shfl_xor(pd[3], off, 64);
      }
      #pragma unroll
      for (int j2 = 0; j2 < 4; ++j2) {
        const float dst = fmaf(-2.f, pd[j2], esq[kbase + j2]);
        if (dst < bd) { bd = dst; bi = kbase + j2; }
      }
    }
    if (lane == 0) {
      uint32_t ub = __float_as_uint(bd);
      ub = (ub & 0x80000000u) ? ~ub : (ub | 0x80000000u);
      const unsigned long long pk =
          ((unsigned long long)ub << 32) | (unsigned)bi;
      atomicMin(&rmin[n], pk);
    }
  }
}

// ---------------- repair pass 2: write repaired rows ----------------
__global__ void repair2_kernel(const float* __restrict__ es,
                               const float* __restrict__ usage,
                               const int* __restrict__ list,
                               const int* __restrict__ counter,
                               const unsigned long long* __restrict__ rmin,
                               float* __restrict__ out_q,
                               float* __restrict__ out_i) {
  const int t   = threadIdx.x;
  const int cnt = *counter;
  for (int j = blockIdx.x; j < cnt; j += 1024) {
    const int n   = list[j];
    const int idx = (int)(rmin[n] & 0x7fffffffu);
    const float u = fmaxf(usage[idx], EPSILON);
    out_q[(size_t)n * D + t] = es[(size_t)idx * D + t] / u;
    if (t == 0) out_i[n] = (float)idx;
  }
}

// ---------------- fallback path (R1, fp32 vector) ----------------
constexpr int TN = 128;
constexpr int DC = 32;
constexpr int KS = 2;
constexpr int RS = 196;

__global__ void esq_kernel(const float* __restrict__ es,
                           const float* __restrict__ usage,
                           float* __restrict__ esq) {
  const int lane = threadIdx.x & 63;
  const int w    = threadIdx.x >> 6;
  const int k    = blockIdx.x * 4 + w;
  const float u  = fmaxf(usage[k], EPSILON);
  const float4 e = *(const float4*)(es + (size_t)k * D + lane * 4);
  const float a = e.x / u, b = e.y / u, c = e.z / u, d = e.w / u;
  float s = a * a + b * b + c * c + d * d;
  #pragma unroll
  for (int m = 1; m < 64; m <<= 1) s += __shfl_xor(s, m, 64);
  if (lane == 0) esq[k] = s;
}

__global__ __launch_bounds__(256, 2)
void dist_kernel(const float* __restrict__ x,
                 const float* __restrict__ es,
                 const float* __restrict__ usage,
                 const float* __restrict__ esq,
                 float* __restrict__ bestd,
                 int* __restrict__ besti, int N) {
  __shared__ float smX[DC * RS];
  __shared__ float smE[DC * RS];
  const int t    = threadIdx.x;
  const int tx   = t & 15;
  const int ty   = t >> 4;
  const int n0   = blockIdx.x * TN;
  const int half = blockIdx.y;

  float best[8];
  int   bidx[8];
  #pragma unroll
  for (int i = 0; i < 8; ++i) { best[i] = FLT_MAX; bidx[i] = 0; }

  for (int kt = 0; kt < (K_TOT / KS) / 128; ++kt) {
    const int k0 = half * (K_TOT / KS) + kt * 128;
    float acc[8][8];
    #pragma unroll
    for (int i = 0; i < 8; ++i)
      #pragma unroll
      for (int j = 0; j < 8; ++j) acc[i][j] = 0.f;

    for (int dc = 0; dc < D; dc += DC) {
      __syncthreads();
      #pragma unroll
      for (int i = 0; i < 4; ++i) {
        const int f    = i * 256 + t;
        const int row  = f >> 3;
        const int c4   = f & 7;
        const int pcol = row + ((row >> 3) << 2);
        const float4 xv =
            *(const float4*)(x + (size_t)(n0 + row) * D + dc + c4 * 4);
        smX[(c4 * 4 + 0) * RS + pcol] = xv.x;
        smX[(c4 * 4 + 1) * RS + pcol] = xv.y;
        smX[(c4 * 4 + 2) * RS + pcol] = xv.z;
        smX[(c4 * 4 + 3) * RS + pcol] = xv.w;
        const int kk = k0 + row;
        const float rs = 1.0f / fmaxf(usage[kk], EPSILON);
        const float4 ev =
            *(const float4*)(es + (size_t)kk * D + dc + c4 * 4);
        smE[(c4 * 4 + 0) * RS + pcol] = ev.x * rs;
        smE[(c4 * 4 + 1) * RS + pcol] = ev.y * rs;
        smE[(c4 * 4 + 2) * RS + pcol] = ev.z * rs;
        smE[(c4 * 4 + 3) * RS + pcol] = ev.w * rs;
      }
      __syncthreads();
      #pragma unroll 4
      for (int d = 0; d < DC; ++d) {
        const float* px = &smX[d * RS + ty * 12];
        const float* pe = &smE[d * RS + tx * 12];
        const float4 xa = *(const float4*)px;
        const float4 xb = *(const float4*)(px + 4);
        const float4 ea = *(const float4*)pe;
        const float4 eb = *(const float4*)(pe + 4);
        const float xr[8] = {xa.x, xa.y, xa.z, xa.w, xb.x, xb.y, xb.z, xb.w};
        const float er[8] = {ea.x, ea.y, ea.z, ea.w, eb.x, eb.y, eb.z, eb.w};
        #pragma unroll
        for (int i = 0; i < 8; ++i)
          #pragma unroll
          for (int jj = 0; jj < 8; ++jj)
            acc[i][jj] = fmaf(xr[i], er[jj], acc[i][jj]);
      }
    }
    #pragma unroll
    for (int jj = 0; jj < 8; ++jj) {
      const int k = k0 + tx * 8 + jj;
      const float eq = esq[k];
      #pragma unroll
      for (int i = 0; i < 8; ++i) {
        const float dst = fmaf(-2.0f, acc[i][jj], eq);
        if (dst < best[i]) { best[i] = dst; bidx[i] = k; }
      }
    }
  }
  __syncthreads();
  float* rd = smX;
  int*   ri = (int*)smE;
  #pragma unroll
  for (int i = 0; i < 8; ++i) {
    const int r = ty * 8 + i;
    rd[tx * TN + r] = best[i];
    ri[tx * TN + r] = bidx[i];
  }
  __syncthreads();
  for (int off = 8; off >= 1; off >>= 1) {
    if (tx < off) {
      #pragma unroll
      for (int i = 0; i < 8; ++i) {
        const int r = ty * 8 + i;
        const float da = rd[tx * TN + r], db = rd[(tx + off) * TN + r];
        const int   ia = ri[tx * TN + r], ib = ri[(tx + off) * TN + r];
        if (db < da || (db == da && ib < ia)) {
          rd[tx * TN + r] = db;
          ri[tx * TN + r] = ib;
        }
      }
    }
    __syncthreads();
  }
  if (tx == 0) {
    #pragma unroll
    for (int i = 0; i < 8; ++i) {
      const int r = ty * 8 + i;
      bestd[(size_t)half * N + n0 + r] = rd[r];
      besti[(size_t)half * N + n0 + r] = ri[r];
    }
  }
}

__global__ void gather_kernel(const float* __restrict__ es,
                              const float* __restrict__ usage,
                              const float* __restrict__ bestd,
                              const int* __restrict__ besti,
                              float* __restrict__ out_q,
                              float* __restrict__ out_i, int N) {
  const int w    = threadIdx.x >> 6;
  const int lane = threadIdx.x & 63;
  const int n    = blockIdx.x * 4 + w;
  const float d0 = bestd[n];
  const float d1 = bestd[(size_t)N + n];
  const int   i0 = besti[n];
  const int   i1 = besti[(size_t)N + n];
  const int idx = (d1 < d0) ? i1 : i0;
  const float u = fmaxf(usage[idx], EPSILON);
  const float4 e = *(const float4*)(es + (size_t)idx * D + lane * 4);
  float4 qv;
  qv.x = e.x / u; qv.y = e.y / u; qv.z = e.z / u; qv.w = e.w / u;
  *(float4*)(out_q + (size_t)n * D + lane * 4) = qv;
  if (lane == 0) out_i[n] = (float)idx;
}

// ---------------- launch ----------------
extern "C" void kernel_launch(void* const* d_in, const int* in_sizes, int n_in,
                              void* d_out, int out_size, void* d_ws, size_t ws_size,
                              hipStream_t stream) {
  const float* x     = (const float*)d_in[0];  // [N, 256]
  const float* es    = (const float*)d_in[1];  // [2048, 256]
  const float* usage = (const float*)d_in[2];  // [2048]
  const int N = in_sizes[0] / D;               // 32768

  float* out_q = (float*)d_out;
  float* out_i = out_q + (size_t)N * D;

  const size_t EB = (size_t)K_TOT * 512 * 2;    // ec: 2 MB
  const size_t off_esq  = EB;
  const size_t off_list = off_esq + 8192;
  const size_t off_cnt  = off_list + (size_t)N * 4;
  const size_t off_rmin = off_cnt + 16;
  const size_t NEED     = off_rmin + (size_t)N * 8;

  char* wsb = (char*)d_ws;

  hipError_t attr_ok = hipFuncSetAttribute(
      (const void*)mm_kernel, hipFuncAttributeMaxDynamicSharedMemorySize,
      DYN_LDS);

  if (ws_size >= NEED && attr_ok == hipSuccess && (N % 128) == 0) {
    _Float16* ec   = (_Float16*)wsb;
    float*    esq  = (float*)(wsb + off_esq);
    int*      list = (int*)(wsb + off_list);
    int*      cnt  = (int*)(wsb + off_cnt);
    unsigned long long* rmin = (unsigned long long*)(wsb + off_rmin);

    prep_kernel<<<K_TOT / 4 + 1, 256, 0, stream>>>(es, usage, ec, esq, cnt);
    mm_kernel<<<N / 128, 512, DYN_LDS, stream>>>(x, ec, esq, es, usage,
                                                 out_q, out_i, list, cnt,
                                                 rmin, N);
    repair_kernel<<<2048, 256, 0, stream>>>(x, es, usage, esq, list, cnt, rmin);
    repair2_kernel<<<1024, 256, 0, stream>>>(es, usage, list, cnt, rmin,
                                             out_q, out_i);
  } else {
    float* ws    = (float*)d_ws;
    float* esq   = ws;
    float* bestd = ws + K_TOT;
    int*   besti = (int*)(ws + K_TOT + (size_t)KS * N);
    esq_kernel<<<K_TOT / 4, 256, 0, stream>>>(es, usage, esq);
    dist_kernel<<<dim3(N / TN, KS), 256, 0, stream>>>(x, es, usage, esq,
                                                      bestd, besti, N);
    gather_kernel<<<N / 4, 256, 0, stream>>>(es, usage, bestd, besti,
                                             out_q, out_i, N);
  }
}